// Round 7
// baseline (182.583 us; speedup 1.0000x reference)
//
#include <hip/hip_runtime.h>
#include <math.h>

// Problem constants: N=128 features, H=256 hidden, B=16 batch.
//
// Analytic collapse of the reference:
//   S = W1^T W1  [256x256] (symmetric), Q = W2 W2^T [256x256] (symmetric)
//   per sample: d = 1-tanh^2(h), c = -2 z d,  P = S diag(d) W2  [256x128]
//   ||dG||_F^2 = 2 sum_{m,m'} c_m c_m' S[m,m'] ( Q[m,m'] R[m,m'] + M[m,m'] M[m',m] )
//        R = P P^T, M = P W2^T
//   Gamma contraction = 0.5*( W2^T (c .* Pv .* Uv) + P^T (c .* W2v .* Uv) )
//   FACTORED P: P = W1^T (W1 diag(d) W2) -- needs NO S => P-blocks fully
//   independent (d recomputed in-block, identical accumulation order).
//
// Session record (dur_us): R1 145.4 -> R2 126.9 -> R3 129.0 -> R4 218.5
// (grid.sync ~35us) -> R5 171.9 -> R6 124.3 -> R7 128.2 -> R8 115.0 ->
// R9 206.8 FAILED (3-deep chain, ~38K RMW pollers) -> R10 149.8 FAILED
// (592 RMW pollers) -> R11 151.6 FAILED (592 READ pollers: poller COUNT is
// the poison, not flavor) -> R12 118.6 (factored P, pmat too coarse) ->
// R13 112.5 BEST (pmat 16 blk/b; fnorm 3-wave scratch 37632B -> 4 blk/CU)
// -> R14 (this): kernel1 rebalance + fnorm latency hiding:
//   (a) pmat_f j-width 4 (512 blocks, ~2 blk/CU during tail; was 1)
//   (b) Q/W2T unmerged to single-tile blocks (kernel1 = 688 independent)
//   (c) fnorm round-2 staging prefetched into registers (+32 VGPR, hides
//       L2 latency; same order => bit-identical)
// LESSONS: (1) grid.sync ~35us - never. (2) wide deps go on KERNEL
// BOUNDARIES; intra-kernel spin only <=16 single-lane pollers, one level.
// (3) occupancy: keep >=2 blk/CU on VALU/LDS-bound bodies. (4) harness
// fixed cost ~82us (268MB ws re-poison); kernel budget ~30us.

// ws layout (float offsets)
static constexpr int OFF_W2T  = 0;        // [128][256]
static constexpr int OFF_S    = 32768;    // [256][256]
static constexpr int OFF_Q    = 98304;    // [256][256]
static constexpr int OFF_D    = 163840;   // [16][256] (legacy; unused now)
static constexpr int OFF_C    = 167936;   // [16][256]
static constexpr int OFF_UV   = 172032;   // [16][256]
static constexpr int OFF_AV   = 176128;   // [16][256]
static constexpr int OFF_VN   = 180224;   // [16]
static constexpr int OFF_SUM  = 180240;   // [16] float accumulator (fnorm^2/2)
static constexpr int OFF_CNT  = 180256;   // [16] int32: fnorm producers done
static constexpr int OFF_PT   = 180288;   // [16][128][256]  PT[b][j][m] = P[b][m][j]
static constexpr int OFF_PN   = OFF_PT + 16 * 32768;  // [16][256][128] row-major P
// total ~= 1.23M floats ~= 4.9 MB

// =====================================================================
// Kernel 1 (688 blocks x 256 thr) -- ALL blocks independent:
//   blk   0.. 63 : S = W1^T W1
//   blk  64..127 : Q = W2 W2^T (single tile)
//   blk 128..159 : W2T transpose (single tile)
//   blk 160..175 : per-sample prep (zero SUM/CNT, out rows 0..15)
//   blk 176..687 : pmat_f: (b = q>>5, jt = q&31) P[:, jt*4..+4) via
//                  P = W1^T (W1 diag(d) W2), d recomputed in-block.
// =====================================================================
__global__ __launch_bounds__(256) void k_stage1d(const float* __restrict__ tptr,
                                                 const float* __restrict__ state,
                                                 const float* __restrict__ x0,
                                                 const float* __restrict__ x1,
                                                 const float* __restrict__ W1,
                                                 const float* __restrict__ b1,
                                                 const float* __restrict__ W2,
                                                 float* __restrict__ ws,
                                                 float* __restrict__ out) {
    __shared__ __align__(16) float lds[8192];   // 32 KB
    int blk = blockIdx.x;
    int tid = threadIdx.x;

    if (blk < 64) {
        // ---- S[m,n] = sum_k W1[k,m] W1[k,n], W1 is [128][256] ----
        float* Ai = lds;             // [32][34] : [k][m]
        float* Aj = lds + 1088;
        int m0 = (blk >> 3) * 32, n0 = (blk & 7) * 32;
        int lx = tid & 31, lr = tid >> 5;
        int tx = tid & 15, ty = tid >> 4;
        float a00 = 0, a01 = 0, a10 = 0, a11 = 0;
        for (int kc = 0; kc < 128; kc += 32) {
            #pragma unroll
            for (int i = 0; i < 4; ++i) {
                int k = lr + 8 * i;
                Ai[k * 34 + lx] = W1[(kc + k) * 256 + m0 + lx];
                Aj[k * 34 + lx] = W1[(kc + k) * 256 + n0 + lx];
            }
            __syncthreads();
            #pragma unroll
            for (int k = 0; k < 32; ++k) {
                float2 a = *(const float2*)&Ai[k * 34 + 2 * ty];
                float2 b = *(const float2*)&Aj[k * 34 + 2 * tx];
                a00 += a.x * b.x; a01 += a.x * b.y;
                a10 += a.y * b.x; a11 += a.y * b.y;
            }
            __syncthreads();
        }
        float* S = ws + OFF_S;
        int m = m0 + 2 * ty, n = n0 + 2 * tx;
        S[m * 256 + n]           = a00;
        S[m * 256 + n + 1]       = a01;
        S[(m + 1) * 256 + n]     = a10;
        S[(m + 1) * 256 + n + 1] = a11;
    } else if (blk < 128) {
        // ---- Q[m,n] = sum_j W2[m,j] W2[n,j], W2 is [256][128] ----
        int bq = blk - 64;
        float* Xi = lds;             // [32][34] : [j][m]
        float* Xj = lds + 1088;
        int m0 = (bq >> 3) * 32, n0 = (bq & 7) * 32;
        int lx = tid & 31, lr = tid >> 5;
        int tx = tid & 15, ty = tid >> 4;
        float a00 = 0, a01 = 0, a10 = 0, a11 = 0;
        for (int kc = 0; kc < 128; kc += 32) {
            #pragma unroll
            for (int i = 0; i < 4; ++i) {
                Xi[lx * 34 + lr + 8 * i] = W2[(m0 + lr + 8 * i) * 128 + kc + lx];
                Xj[lx * 34 + lr + 8 * i] = W2[(n0 + lr + 8 * i) * 128 + kc + lx];
            }
            __syncthreads();
            #pragma unroll
            for (int k = 0; k < 32; ++k) {
                float2 a = *(const float2*)&Xi[k * 34 + 2 * ty];
                float2 b = *(const float2*)&Xj[k * 34 + 2 * tx];
                a00 += a.x * b.x; a01 += a.x * b.y;
                a10 += a.y * b.x; a11 += a.y * b.y;
            }
            __syncthreads();
        }
        float* Q = ws + OFF_Q;
        int m = m0 + 2 * ty, n = n0 + 2 * tx;
        Q[m * 256 + n]           = a00;
        Q[m * 256 + n + 1]       = a01;
        Q[(m + 1) * 256 + n]     = a10;
        Q[(m + 1) * 256 + n + 1] = a11;
    } else if (blk < 160) {
        // ---- W2T[c][r] = W2[r][c] ----
        int b2 = blk - 128;
        float* tile = lds;  // [32][33]
        int c0 = (b2 & 3) * 32, r0 = (b2 >> 2) * 32;
        int tx = tid & 31, ty = tid >> 5;
        #pragma unroll
        for (int i = 0; i < 32; i += 8)
            tile[(ty + i) * 33 + tx] = W2[(r0 + ty + i) * 128 + c0 + tx];
        __syncthreads();
        float* W2T = ws + OFF_W2T;
        #pragma unroll
        for (int i = 0; i < 32; i += 8)
            W2T[(c0 + ty + i) * 256 + r0 + tx] = tile[tx * 33 + ty + i];
    } else if (blk < 176) {
        // ---- per-sample prep ----
        int b = blk - 160;
        float* xs  = lds;
        float* vs  = lds + 128;
        float* red = lds + 256;
        float t = tptr[0];
        float w = 4.f * t * (1.f - t);
        if (tid == 0) {
            ws[OFF_SUM + b] = 0.f;
            ((int*)ws)[OFF_CNT + b] = 0;
        }
        if (tid < 128) {
            float dev = state[b * 128 + tid];
            float v   = state[(16 + b) * 128 + tid];
            float xv  = x0[b * 128 + tid] + t * (x1[b * 128 + tid] - x0[b * 128 + tid]) + w * dev;
            xs[tid] = xv;
            vs[tid] = v;
            out[b * 128 + tid] = v;   // first-half output = dev_velocity
            red[tid] = v * v;
        }
        __syncthreads();
        for (int s = 64; s > 0; s >>= 1) {
            if (tid < s) red[tid] += red[tid + s];
            __syncthreads();
        }
        if (tid == 0) ws[OFF_VN + b] = sqrtf(red[0]);

        int m = tid;  // 0..255
        float h = b1[m], uvm = 0.f;
        #pragma unroll 8
        for (int k = 0; k < 128; ++k) {
            float wv = W1[k * 256 + m];    // coalesced
            h   += xs[k] * wv;
            uvm += vs[k] * wv;
        }
        float z  = tanhf(h);
        float dd = 1.f - z * z;
        float cc = -2.f * z * dd;
        const float4* w2r = (const float4*)&W2[m * 128];
        const float4* vs4 = (const float4*)vs;
        float avm = 0.f;
        #pragma unroll 8
        for (int j4 = 0; j4 < 32; ++j4) {
            float4 ww = w2r[j4];
            float4 vv = vs4[j4];
            avm += ww.x * vv.x + ww.y * vv.y + ww.z * vv.z + ww.w * vv.w;
        }
        ws[OFF_D  + b * 256 + m] = dd;
        ws[OFF_C  + b * 256 + m] = cc;
        ws[OFF_UV + b * 256 + m] = uvm;
        ws[OFF_AV + b * 256 + m] = avm;
    } else {
        // ---- pmat_f: P[:, j0..j0+4) = W1^T (W1 diag(d) W2[:, j0..j0+4)) ----
        int q = blk - 176;
        int b = q >> 5, jt = q & 31, j0 = jt * 4;
        float* xs  = lds;            // [128]
        float* dsv = lds + 128;      // [256]
        float* W1s = lds + 384;      // [128][36] n-chunk of W1 (4608)
        float* YdT = lds + 4992;     // [4][36]  (d*W2)^T chunk  (144)
        float* Fl  = lds + 5136;     // [128][4] F slice         (512) -> 5648
        float t = tptr[0];
        float w = 4.f * t * (1.f - t);
        if (tid < 128) {
            float dev = state[b * 128 + tid];
            xs[tid] = x0[b * 128 + tid] + t * (x1[b * 128 + tid] - x0[b * 128 + tid]) + w * dev;
        }
        __syncthreads();
        {   // d[m] = 1 - tanh^2(h[m])  (identical loop to prep -> identical values)
            int m = tid;
            float h = b1[m];
            #pragma unroll 8
            for (int k = 0; k < 128; ++k) h += xs[k] * W1[k * 256 + m];
            float z = tanhf(h);
            dsv[m] = 1.f - z * z;
        }
        __syncthreads();

        // phase 1: F[k][j] = sum_n W1[k][n] * dsv[n] * W2[n][j0+j], j in [0,4)
        float facc[2] = {};
        int pj = tid & 3, pk = tid >> 2;    // pk in [0,64); k = pk + 64*kk
        for (int nc = 0; nc < 256; nc += 32) {
            {   // stage W1s[r][nn] = W1[r][nc+nn], 128x32
                int r = tid >> 1, h16 = (tid & 1) * 16;
                #pragma unroll
                for (int c = 0; c < 4; ++c)
                    *(float4*)&W1s[r * 36 + h16 + 4 * c] =
                        *(const float4*)&W1[r * 256 + nc + h16 + 4 * c];
            }
            if (tid < 32) {  // stage YdT[j][nn] = dsv[nc+nn]*W2[(nc+nn)][j0+j]
                int n2 = tid;
                float4 wv = *(const float4*)&W2[(nc + n2) * 128 + j0];
                float dn = dsv[nc + n2];
                YdT[0 * 36 + n2] = wv.x * dn;
                YdT[1 * 36 + n2] = wv.y * dn;
                YdT[2 * 36 + n2] = wv.z * dn;
                YdT[3 * 36 + n2] = wv.w * dn;
            }
            __syncthreads();
            #pragma unroll
            for (int nn = 0; nn < 32; nn += 4) {
                float4 yv = *(const float4*)&YdT[pj * 36 + nn];
                #pragma unroll
                for (int kk = 0; kk < 2; ++kk) {
                    float4 wv = *(const float4*)&W1s[(pk + 64 * kk) * 36 + nn];
                    facc[kk] += wv.x * yv.x; facc[kk] += wv.y * yv.y;
                    facc[kk] += wv.z * yv.z; facc[kk] += wv.w * yv.w;
                }
            }
            __syncthreads();
        }
        #pragma unroll
        for (int kk = 0; kk < 2; ++kk)
            Fl[(pk + 64 * kk) * 4 + pj] = facc[kk];   // = tid + 256*kk: conflict-free
        __syncthreads();

        // phase 2: P[m][j0+j] = sum_k W1[k][m] * F[k][j]
        float acc2[4] = {};
        int m = tid;
        #pragma unroll 4
        for (int k = 0; k < 128; ++k) {
            float wv = W1[k * 256 + m];            // coalesced, L2-hot
            float4 f0 = *(const float4*)&Fl[k * 4];   // broadcast read
            acc2[0] += wv * f0.x; acc2[1] += wv * f0.y;
            acc2[2] += wv * f0.z; acc2[3] += wv * f0.w;
        }
        float* ptb = ws + OFF_PT + b * 32768;
        float* pnb = ws + OFF_PN + b * 32768;
        #pragma unroll
        for (int jj = 0; jj < 4; ++jj)
            ptb[(j0 + jj) * 256 + m] = acc2[jj];   // coalesced over m
        *(float4*)&pnb[m * 128 + j0] = make_float4(acc2[0], acc2[1], acc2[2], acc2[3]);
    }
}

// =====================================================================
// Kernel 2: fnorm + epilogue. Grid 592 x 256 thr, all-resident
// (LDS 37632B + launch_bounds(256,4) => 4 blk/CU capacity; grid-limited
// at ~2-3 blk/CU).
//   blk  0..15 : per-b epilogue (pv/g1/g2/raw overlap producers; only the
//                snrm scaling spin-waits on CNT[b]==36 -- R8 envelope)
//   blk 16..591: triangular (mi,mj) Frobenius tiles, 4 waves x j-quarter,
//                2-round j staging (round-2 REGISTER-PREFETCHED) + 3-wave
//                reduction scratch. Same accumulation orders as R13.
// =====================================================================
__global__ __launch_bounds__(256, 4) void k_fnorm8(const float* __restrict__ state,
                                                   const float* __restrict__ W2,
                                                   float* __restrict__ ws,
                                                   float* __restrict__ out) {
    __shared__ __align__(16) float lds[9408];   // 37632 B
    int blk = blockIdx.x;
    int tid = threadIdx.x;
    int* cnt = (int*)ws + OFF_CNT;

    if (blk < 16) {
        // ================= epilogue path =================
        int b = blk;
        const float* ptb = ws + OFF_PT + b * 32768;
        const float* pnb = ws + OFF_PN + b * 32768;
        float* vs   = lds;          // [128]
        float* g1   = lds + 128;    // [256]
        float* g2   = lds + 384;    // [256]
        float* red  = lds + 640;    // [256]
        float* snrm = lds + 900;
        if (tid < 128) vs[tid] = state[(16 + b) * 128 + tid];
        __syncthreads();

        int m = tid;
        float pv = 0.f;
        #pragma unroll 8
        for (int j = 0; j < 128; ++j)
            pv += ptb[j * 256 + m] * vs[j];     // coalesced over m
        float cc  = ws[OFF_C  + b * 256 + m];
        float uvm = ws[OFF_UV + b * 256 + m];
        float avm = ws[OFF_AV + b * 256 + m];
        g1[m] = cc * pv  * uvm;
        g2[m] = cc * avm * uvm;
        __syncthreads();

        // raw_i = sum_mm W2[mm,i] g1[mm] + Pn[mm,i] g2[mm]; mm split 2 halves
        int i = tid & 127, half = tid >> 7;
        int mmlo = half * 128;
        float raw = 0.f;
        #pragma unroll 8
        for (int mm = mmlo; mm < mmlo + 128; ++mm)
            raw += W2[mm * 128 + i] * g1[mm] + pnb[mm * 128 + i] * g2[mm];
        red[tid] = raw;
        __syncthreads();

        // Only now wait for the 36 producer blocks of this b.
        if (tid == 0) {
            while (atomicAdd(&cnt[b], 0) < 36) __builtin_amdgcn_s_sleep(2);
            __threadfence();
            float tot = atomicAdd(&ws[OFF_SUM + b], 0.0f);  // coherent read
            snrm[0] = sqrtf(fmaxf(2.f * tot, 0.f));
        }
        __syncthreads();
        if (tid < 128) {
            float rawt = red[tid] + red[tid + 128];
            float vn = ws[OFF_VN + b];
            float a  = -0.5f * rawt / ((snrm[0] + 1e-6f) * (vn + 1e-6f));
            out[(16 + b) * 128 + tid] = a - 0.1f * state[b * 128 + tid];
        }
        return;
    }

    // ================= producer path =================
    int q   = blk - 16;
    int idx = q >> 4;          // 0..35 triangular tile
    int b   = q & 15;
    int tj = 0;
    while ((tj + 1) * (tj + 2) / 2 <= idx) ++tj;
    int ti = idx - tj * (tj + 1) / 2;      // ti <= tj
    int mi0 = ti * 32, mj0 = tj * 32;
    float* PiT = lds;              // [64][32] per round
    float* PjT = lds + 2048;
    float* WiT = lds + 4096;
    float* WjT = lds + 6144;
    const float* ptb  = ws + OFF_PT + b * 32768;
    const float* W2T  = ws + OFF_W2T;
    const float* Smat = ws + OFF_S;
    const float* Qmat = ws + OFF_Q;
    int jr = tid >> 3, jc4 = (tid & 7) * 4;
    int w = tid >> 6, s = tid & 63;
    int ty = s >> 3, tx = s & 7;
    float r[4][4] = {}, f[4][4] = {}, g[4][4] = {};
    // Two staging rounds; round rr uses global j = 32*(l>>4)+16*rr+(l&15)
    // for local row l: wave w's rows [16w,16w+16) -> same per-wave j set &
    // order as R13/R8. Round-2 panels are PREFETCHED into registers while
    // round-1 computes (same values, same order -> bit-identical).
    float4 rPi[2], rPj[2], rWi[2], rWj[2];
    #pragma unroll
    for (int it = 0; it < 2; ++it) {     // prefetch round 0
        int l = jr + 32 * it;
        int j = 32 * (l >> 4) + (l & 15);
        rPi[it] = *(const float4*)&ptb[j * 256 + mi0 + jc4];
        rPj[it] = *(const float4*)&ptb[j * 256 + mj0 + jc4];
        rWi[it] = *(const float4*)&W2T[j * 256 + mi0 + jc4];
        rWj[it] = *(const float4*)&W2T[j * 256 + mj0 + jc4];
    }
    #pragma unroll
    for (int rr = 0; rr < 2; ++rr) {
        #pragma unroll
        for (int it = 0; it < 2; ++it) {
            int l = jr + 32 * it;
            *(float4*)&PiT[l * 32 + jc4] = rPi[it];
            *(float4*)&PjT[l * 32 + jc4] = rPj[it];
            *(float4*)&WiT[l * 32 + jc4] = rWi[it];
            *(float4*)&WjT[l * 32 + jc4] = rWj[it];
        }
        __syncthreads();
        if (rr == 0) {
            #pragma unroll
            for (int it = 0; it < 2; ++it) {   // prefetch round 1 (hidden under compute)
                int l = jr + 32 * it;
                int j = 32 * (l >> 4) + 16 + (l & 15);
                rPi[it] = *(const float4*)&ptb[j * 256 + mi0 + jc4];
                rPj[it] = *(const float4*)&ptb[j * 256 + mj0 + jc4];
                rWi[it] = *(const float4*)&W2T[j * 256 + mi0 + jc4];
                rWj[it] = *(const float4*)&W2T[j * 256 + mj0 + jc4];
            }
        }
        #pragma unroll 4
        for (int jj = 0; jj < 16; ++jj) {
            int l = 16 * w + jj;
            float4 pi4 = *(const float4*)&PiT[l * 32 + 4 * ty];
            float4 pj4 = *(const float4*)&PjT[l * 32 + 4 * tx];
            float4 wi4 = *(const float4*)&WiT[l * 32 + 4 * ty];
            float4 wj4 = *(const float4*)&WjT[l * 32 + 4 * tx];
            float pi[4] = {pi4.x, pi4.y, pi4.z, pi4.w};
            float pj[4] = {pj4.x, pj4.y, pj4.z, pj4.w};
            float wi[4] = {wi4.x, wi4.y, wi4.z, wi4.w};
            float wj[4] = {wj4.x, wj4.y, wj4.z, wj4.w};
            #pragma unroll
            for (int ii = 0; ii < 4; ++ii)
                #pragma unroll
                for (int kk = 0; kk < 4; ++kk) {
                    r[ii][kk] += pi[ii] * pj[kk];   // R[mi,mj]
                    f[ii][kk] += pi[ii] * wj[kk];   // M[mi,mj]
                    g[ii][kk] += pj[kk] * wi[ii];   // M[mj,mi]
                }
        }
        __syncthreads();   // round rr done; safe to restage / reuse as scratch
    }
    // 3-wave scratch: waves 1..3 spill; wave 0 keeps registers.
    if (w != 0) {
        float* scr = lds;
        int base = ((w - 1) * 64 + s) * 49;   // stride 49: conflict-light
        #pragma unroll
        for (int ii = 0; ii < 4; ++ii)
            #pragma unroll
            for (int kk = 0; kk < 4; ++kk) {
                scr[base + ii * 4 + kk]      = r[ii][kk];
                scr[base + 16 + ii * 4 + kk] = f[ii][kk];
                scr[base + 32 + ii * 4 + kk] = g[ii][kk];
            }
    }
    __syncthreads();
    if (tid < 64) {
        float tr[16], tf[16], tg[16];
        #pragma unroll
        for (int ii = 0; ii < 4; ++ii)
            #pragma unroll
            for (int kk = 0; kk < 4; ++kk) {
                tr[ii * 4 + kk] = r[ii][kk];
                tf[ii * 4 + kk] = f[ii][kk];
                tg[ii * 4 + kk] = g[ii][kk];
            }
        // add waves 1..3 in order -> same w0+w1+w2+w3 order as R8
        for (int ww = 0; ww < 3; ++ww) {
            const float* sc = lds + (ww * 64 + tid) * 49;
            #pragma unroll
            for (int k = 0; k < 16; ++k) {
                tr[k] += sc[k];
                tf[k] += sc[16 + k];
                tg[k] += sc[32 + k];
            }
        }
        const float* cb = ws + OFF_C + b * 256;
        int mi = mi0 + 4 * (tid >> 3), mj = mj0 + 4 * (tid & 7);
        float4 ce4 = *(const float4*)&cb[mj];
        float ce[4] = {ce4.x, ce4.y, ce4.z, ce4.w};
        float sum = 0.f;
        #pragma unroll
        for (int ii = 0; ii < 4; ++ii) {
            float ci = cb[mi + ii];
            float4 S4 = *(const float4*)&Smat[(mi + ii) * 256 + mj];
            float4 Q4 = *(const float4*)&Qmat[(mi + ii) * 256 + mj];
            float Sv[4] = {S4.x, S4.y, S4.z, S4.w};
            float Qv[4] = {Q4.x, Q4.y, Q4.z, Q4.w};
            #pragma unroll
            for (int kk = 0; kk < 4; ++kk)
                sum += ci * ce[kk] * Sv[kk] * (Qv[kk] * tr[ii * 4 + kk] + tf[ii * 4 + kk] * tg[ii * 4 + kk]);
        }
        if (ti < tj) sum *= 2.f;
        #pragma unroll
        for (int off = 32; off > 0; off >>= 1)
            sum += __shfl_down(sum, off);
        if (tid == 0) {
            atomicAdd(&ws[OFF_SUM + b], sum);
            __threadfence();
            atomicAdd(&cnt[b], 1);   // release: epilogue block b may finish
        }
    }
}

extern "C" void kernel_launch(void* const* d_in, const int* in_sizes, int n_in,
                              void* d_out, int out_size, void* d_ws, size_t ws_size,
                              hipStream_t stream) {
    (void)in_sizes; (void)n_in; (void)out_size; (void)ws_size;
    const float* t     = (const float*)d_in[0];
    const float* state = (const float*)d_in[1];
    const float* x0    = (const float*)d_in[2];
    const float* x1    = (const float*)d_in[3];
    const float* W1    = (const float*)d_in[4];
    const float* b1    = (const float*)d_in[5];
    const float* W2    = (const float*)d_in[6];
    // b2 cancels in the Jacobian — unused.
    float* out = (float*)d_out;
    float* ws  = (float*)d_ws;

    k_stage1d<<<688, 256, 0, stream>>>(t, state, x0, x1, W1, b1, W2, ws, out);
    k_fnorm8<<<592, 256, 0, stream>>>(state, W2, ws, out);
}

// Round 9
// 112.390 us; speedup vs baseline: 1.6245x; 1.6245x over previous
//
#include <hip/hip_runtime.h>
#include <math.h>

// Problem constants: N=128 features, H=256 hidden, B=16 batch.
//
// Analytic collapse of the reference:
//   S = W1^T W1  [256x256] (symmetric), Q = W2 W2^T [256x256] (symmetric)
//   per sample: d = 1-tanh^2(h), c = -2 z d,  P = S diag(d) W2  [256x128]
//   ||dG||_F^2 = 2 sum_{m,m'} c_m c_m' S[m,m'] ( Q[m,m'] R[m,m'] + M[m,m'] M[m',m] )
//        R = P P^T, M = P W2^T
//   Gamma contraction = 0.5*( W2^T (c .* Pv .* Uv) + P^T (c .* W2v .* Uv) )
//   FACTORED P: P = W1^T (W1 diag(d) W2) -- same 16.8 MFLOP/sample as
//   S diag(d) W2 but needs NO S => P-blocks fully independent (d recomputed
//   in-block, identical accumulation order to prep's d).
//
// Session record (dur_us): R1 145.4 -> R2 126.9 -> R3 129.0 -> R4 218.5
// (grid.sync ~35us) -> R5 171.9 -> R6 124.3 -> R7 128.2 -> R8 115.0
// (3 kernels; 16 single-lane spin epilogue blocks: FINE) -> R9 206.8 FAILED
// (3-deep chain, ~38K RMW pollers) -> R10 149.8 FAILED (592 RMW pollers) ->
// R11 151.6 FAILED (592 READ pollers: poller COUNT is the poison, not
// flavor) -> R12 118.6 (factored P, pmat too coarse) -> R13 112.5 BEST
// (pmat 16 blk/b; fnorm 3-wave scratch 37632B -> 4 blk/CU) -> R14 182.6
// FAILED: pmat j-width 4 repartition flipped codegen into VGPR_Count=256 +
// ~100MB/dispatch scratch-spill writes (compiler cliff, not resource math;
// fnorm reg-prefetch was neutral). -> R15: revert to R13 verbatim; bench
// infra failed (container acquisition, no kernel signal). -> R16 (this):
// resubmit R13 verbatim unchanged.
// LESSONS: (1) grid.sync ~35us - never. (2) wide deps go on KERNEL
// BOUNDARIES; intra-kernel spin only <=16 single-lane pollers, one level.
// (3) occupancy: keep >=2 blk/CU on VALU/LDS-bound bodies. (4) check
// VGPR_Count after ANY partition change - multi-branch kernels can cliff
// into spills. (5) harness fixed cost ~82us; kernel budget ~30us.

// ws layout (float offsets)
static constexpr int OFF_W2T  = 0;        // [128][256]
static constexpr int OFF_S    = 32768;    // [256][256]
static constexpr int OFF_Q    = 98304;    // [256][256]
static constexpr int OFF_D    = 163840;   // [16][256] (legacy; unused now)
static constexpr int OFF_C    = 167936;   // [16][256]
static constexpr int OFF_UV   = 172032;   // [16][256]
static constexpr int OFF_AV   = 176128;   // [16][256]
static constexpr int OFF_VN   = 180224;   // [16]
static constexpr int OFF_SUM  = 180240;   // [16] float accumulator (fnorm^2/2)
static constexpr int OFF_CNT  = 180256;   // [16] int32: fnorm producers done
static constexpr int OFF_PT   = 180288;   // [16][128][256]  PT[b][j][m] = P[b][m][j]
static constexpr int OFF_PN   = OFF_PT + 16 * 32768;  // [16][256][128] row-major P
// total ~= 1.23M floats ~= 4.9 MB

// =====================================================================
// Kernel 1 (384 blocks x 256 thr) -- ALL blocks independent:
//   blk   0.. 63 : S = W1^T W1
//   blk  64.. 95 : Q = W2 W2^T (2 tiles each)
//   blk  96..111 : W2T transpose (2 tiles each)
//   blk 112..127 : per-sample prep (zero SUM/CNT, out rows 0..15)
//   blk 128..383 : pmat_f: (b = q>>4, jt = q&15) P[:, jt*8..+8) via
//                  P = W1^T (W1 diag(d) W2), d recomputed in-block.
// =====================================================================
__global__ __launch_bounds__(256) void k_stage1c(const float* __restrict__ tptr,
                                                 const float* __restrict__ state,
                                                 const float* __restrict__ x0,
                                                 const float* __restrict__ x1,
                                                 const float* __restrict__ W1,
                                                 const float* __restrict__ b1,
                                                 const float* __restrict__ W2,
                                                 float* __restrict__ ws,
                                                 float* __restrict__ out) {
    __shared__ __align__(16) float lds[8192];   // 32 KB
    int blk = blockIdx.x;
    int tid = threadIdx.x;

    if (blk < 64) {
        // ---- S[m,n] = sum_k W1[k,m] W1[k,n], W1 is [128][256] ----
        float* Ai = lds;             // [32][34] : [k][m]
        float* Aj = lds + 1088;
        int m0 = (blk >> 3) * 32, n0 = (blk & 7) * 32;
        int lx = tid & 31, lr = tid >> 5;
        int tx = tid & 15, ty = tid >> 4;
        float a00 = 0, a01 = 0, a10 = 0, a11 = 0;
        for (int kc = 0; kc < 128; kc += 32) {
            #pragma unroll
            for (int i = 0; i < 4; ++i) {
                int k = lr + 8 * i;
                Ai[k * 34 + lx] = W1[(kc + k) * 256 + m0 + lx];
                Aj[k * 34 + lx] = W1[(kc + k) * 256 + n0 + lx];
            }
            __syncthreads();
            #pragma unroll
            for (int k = 0; k < 32; ++k) {
                float2 a = *(const float2*)&Ai[k * 34 + 2 * ty];
                float2 b = *(const float2*)&Aj[k * 34 + 2 * tx];
                a00 += a.x * b.x; a01 += a.x * b.y;
                a10 += a.y * b.x; a11 += a.y * b.y;
            }
            __syncthreads();
        }
        float* S = ws + OFF_S;
        int m = m0 + 2 * ty, n = n0 + 2 * tx;
        S[m * 256 + n]           = a00;
        S[m * 256 + n + 1]       = a01;
        S[(m + 1) * 256 + n]     = a10;
        S[(m + 1) * 256 + n + 1] = a11;
    } else if (blk < 96) {
        // ---- Q[m,n] = sum_j W2[m,j] W2[n,j]; 2 tiles per block ----
        int bqq = blk - 64;
        for (int hh = 0; hh < 2; ++hh) {
            int bq = bqq + 32 * hh;
            float* Xi = lds;         // [32][34] : [j][m]
            float* Xj = lds + 1088;
            int m0 = (bq >> 3) * 32, n0 = (bq & 7) * 32;
            int lx = tid & 31, lr = tid >> 5;
            int tx = tid & 15, ty = tid >> 4;
            float a00 = 0, a01 = 0, a10 = 0, a11 = 0;
            for (int kc = 0; kc < 128; kc += 32) {
                #pragma unroll
                for (int i = 0; i < 4; ++i) {
                    Xi[lx * 34 + lr + 8 * i] = W2[(m0 + lr + 8 * i) * 128 + kc + lx];
                    Xj[lx * 34 + lr + 8 * i] = W2[(n0 + lr + 8 * i) * 128 + kc + lx];
                }
                __syncthreads();
                #pragma unroll
                for (int k = 0; k < 32; ++k) {
                    float2 a = *(const float2*)&Xi[k * 34 + 2 * ty];
                    float2 b = *(const float2*)&Xj[k * 34 + 2 * tx];
                    a00 += a.x * b.x; a01 += a.x * b.y;
                    a10 += a.y * b.x; a11 += a.y * b.y;
                }
                __syncthreads();
            }
            float* Q = ws + OFF_Q;
            int m = m0 + 2 * ty, n = n0 + 2 * tx;
            Q[m * 256 + n]           = a00;
            Q[m * 256 + n + 1]       = a01;
            Q[(m + 1) * 256 + n]     = a10;
            Q[(m + 1) * 256 + n + 1] = a11;
            __syncthreads();
        }
    } else if (blk < 112) {
        // ---- W2T[c][r] = W2[r][c]; 2 tiles per block ----
        int bt = blk - 96;
        for (int hh = 0; hh < 2; ++hh) {
            int b2 = bt + 16 * hh;
            float* tile = lds;  // [32][33]
            int c0 = (b2 & 3) * 32, r0 = (b2 >> 2) * 32;
            int tx = tid & 31, ty = tid >> 5;
            #pragma unroll
            for (int i = 0; i < 32; i += 8)
                tile[(ty + i) * 33 + tx] = W2[(r0 + ty + i) * 128 + c0 + tx];
            __syncthreads();
            float* W2T = ws + OFF_W2T;
            #pragma unroll
            for (int i = 0; i < 32; i += 8)
                W2T[(c0 + ty + i) * 256 + r0 + tx] = tile[tx * 33 + ty + i];
            __syncthreads();
        }
    } else if (blk < 128) {
        // ---- per-sample prep ----
        int b = blk - 112;
        float* xs  = lds;
        float* vs  = lds + 128;
        float* red = lds + 256;
        float t = tptr[0];
        float w = 4.f * t * (1.f - t);
        if (tid == 0) {
            ws[OFF_SUM + b] = 0.f;
            ((int*)ws)[OFF_CNT + b] = 0;
        }
        if (tid < 128) {
            float dev = state[b * 128 + tid];
            float v   = state[(16 + b) * 128 + tid];
            float xv  = x0[b * 128 + tid] + t * (x1[b * 128 + tid] - x0[b * 128 + tid]) + w * dev;
            xs[tid] = xv;
            vs[tid] = v;
            out[b * 128 + tid] = v;   // first-half output = dev_velocity
            red[tid] = v * v;
        }
        __syncthreads();
        for (int s = 64; s > 0; s >>= 1) {
            if (tid < s) red[tid] += red[tid + s];
            __syncthreads();
        }
        if (tid == 0) ws[OFF_VN + b] = sqrtf(red[0]);

        int m = tid;  // 0..255
        float h = b1[m], uvm = 0.f;
        #pragma unroll 8
        for (int k = 0; k < 128; ++k) {
            float wv = W1[k * 256 + m];    // coalesced
            h   += xs[k] * wv;
            uvm += vs[k] * wv;
        }
        float z  = tanhf(h);
        float dd = 1.f - z * z;
        float cc = -2.f * z * dd;
        const float4* w2r = (const float4*)&W2[m * 128];
        const float4* vs4 = (const float4*)vs;
        float avm = 0.f;
        #pragma unroll 8
        for (int j4 = 0; j4 < 32; ++j4) {
            float4 ww = w2r[j4];
            float4 vv = vs4[j4];
            avm += ww.x * vv.x + ww.y * vv.y + ww.z * vv.z + ww.w * vv.w;
        }
        ws[OFF_D  + b * 256 + m] = dd;
        ws[OFF_C  + b * 256 + m] = cc;
        ws[OFF_UV + b * 256 + m] = uvm;
        ws[OFF_AV + b * 256 + m] = avm;
    } else {
        // ---- pmat_f: P[:, j0..j0+8) = W1^T (W1 diag(d) W2[:, j0..j0+8)) ----
        int q = blk - 128;
        int b = q >> 4, jt = q & 15, j0 = jt * 8;
        float* xs  = lds;            // [128]
        float* dsv = lds + 128;      // [256]
        float* W1s = lds + 384;      // [128][36] n-chunk of W1 (4608)
        float* YdT = lds + 4992;     // [8][36]  (d*W2)^T chunk  (288)
        float* Fl  = lds + 5280;     // [128][12] F slice        (1536) -> 6816
        float t = tptr[0];
        float w = 4.f * t * (1.f - t);
        if (tid < 128) {
            float dev = state[b * 128 + tid];
            xs[tid] = x0[b * 128 + tid] + t * (x1[b * 128 + tid] - x0[b * 128 + tid]) + w * dev;
        }
        __syncthreads();
        {   // d[m] = 1 - tanh^2(h[m])  (identical loop to prep -> identical values)
            int m = tid;
            float h = b1[m];
            #pragma unroll 8
            for (int k = 0; k < 128; ++k) h += xs[k] * W1[k * 256 + m];
            float z = tanhf(h);
            dsv[m] = 1.f - z * z;
        }
        __syncthreads();

        // phase 1: F[k][j] = sum_n W1[k][n] * dsv[n] * W2[n][j0+j], j in [0,8)
        float facc[4] = {};
        int pj = tid & 7, pk = tid >> 3;    // pk in [0,32); k = pk + 32*kk
        for (int nc = 0; nc < 256; nc += 32) {
            {   // stage W1s[r][nn] = W1[r][nc+nn], 128x32
                int r = tid >> 1, h16 = (tid & 1) * 16;
                #pragma unroll
                for (int c = 0; c < 4; ++c)
                    *(float4*)&W1s[r * 36 + h16 + 4 * c] =
                        *(const float4*)&W1[r * 256 + nc + h16 + 4 * c];
            }
            if (tid < 64) {  // stage YdT[j][nn] = dsv[nc+nn]*W2[(nc+nn)][j0+j]
                int n2 = tid >> 1, c4 = (tid & 1) * 4;
                float4 wv = *(const float4*)&W2[(nc + n2) * 128 + j0 + c4];
                float dn = dsv[nc + n2];
                YdT[(c4 + 0) * 36 + n2] = wv.x * dn;
                YdT[(c4 + 1) * 36 + n2] = wv.y * dn;
                YdT[(c4 + 2) * 36 + n2] = wv.z * dn;
                YdT[(c4 + 3) * 36 + n2] = wv.w * dn;
            }
            __syncthreads();
            #pragma unroll
            for (int nn = 0; nn < 32; nn += 4) {
                float4 yv = *(const float4*)&YdT[pj * 36 + nn];
                #pragma unroll
                for (int kk = 0; kk < 4; ++kk) {
                    float4 wv = *(const float4*)&W1s[(pk + 32 * kk) * 36 + nn];
                    facc[kk] += wv.x * yv.x; facc[kk] += wv.y * yv.y;
                    facc[kk] += wv.z * yv.z; facc[kk] += wv.w * yv.w;
                }
            }
            __syncthreads();
        }
        #pragma unroll
        for (int kk = 0; kk < 4; ++kk)
            Fl[(pk + 32 * kk) * 12 + pj] = facc[kk];
        __syncthreads();

        // phase 2: P[m][j0+j] = sum_k W1[k][m] * F[k][j]
        float acc2[8] = {};
        int m = tid;
        #pragma unroll 4
        for (int k = 0; k < 128; ++k) {
            float wv = W1[k * 256 + m];            // coalesced, L2-hot
            float4 f0 = *(const float4*)&Fl[k * 12];
            float4 f1 = *(const float4*)&Fl[k * 12 + 4];   // broadcast reads
            acc2[0] += wv * f0.x; acc2[1] += wv * f0.y;
            acc2[2] += wv * f0.z; acc2[3] += wv * f0.w;
            acc2[4] += wv * f1.x; acc2[5] += wv * f1.y;
            acc2[6] += wv * f1.z; acc2[7] += wv * f1.w;
        }
        float* ptb = ws + OFF_PT + b * 32768;
        float* pnb = ws + OFF_PN + b * 32768;
        #pragma unroll
        for (int jj = 0; jj < 8; ++jj)
            ptb[(j0 + jj) * 256 + m] = acc2[jj];   // coalesced over m
        *(float4*)&pnb[m * 128 + j0]     = make_float4(acc2[0], acc2[1], acc2[2], acc2[3]);
        *(float4*)&pnb[m * 128 + j0 + 4] = make_float4(acc2[4], acc2[5], acc2[6], acc2[7]);
    }
}

// =====================================================================
// Kernel 2: fnorm + epilogue. Grid 592 x 256 thr, all-resident
// (LDS 37632B + launch_bounds(256,4) => 4 blk/CU, 1024 slots >= 592).
//   blk  0..15 : per-b epilogue (pv/g1/g2/raw overlap producers; only the
//                snrm scaling spin-waits on CNT[b]==36 -- R8 envelope)
//   blk 16..591: triangular (mi,mj) Frobenius tiles, 4 waves x j-quarter,
//                2-round j staging + 3-wave reduction scratch (R9-proven
//                bit-identical body).
// =====================================================================
__global__ __launch_bounds__(256, 4) void k_fnorm7(const float* __restrict__ state,
                                                   const float* __restrict__ W2,
                                                   float* __restrict__ ws,
                                                   float* __restrict__ out) {
    __shared__ __align__(16) float lds[9408];   // 37632 B
    int blk = blockIdx.x;
    int tid = threadIdx.x;
    int* cnt = (int*)ws + OFF_CNT;

    if (blk < 16) {
        // ================= epilogue path =================
        int b = blk;
        const float* ptb = ws + OFF_PT + b * 32768;
        const float* pnb = ws + OFF_PN + b * 32768;
        float* vs   = lds;          // [128]
        float* g1   = lds + 128;    // [256]
        float* g2   = lds + 384;    // [256]
        float* red  = lds + 640;    // [256]
        float* snrm = lds + 900;
        if (tid < 128) vs[tid] = state[(16 + b) * 128 + tid];
        __syncthreads();

        int m = tid;
        float pv = 0.f;
        #pragma unroll 8
        for (int j = 0; j < 128; ++j)
            pv += ptb[j * 256 + m] * vs[j];     // coalesced over m
        float cc  = ws[OFF_C  + b * 256 + m];
        float uvm = ws[OFF_UV + b * 256 + m];
        float avm = ws[OFF_AV + b * 256 + m];
        g1[m] = cc * pv  * uvm;
        g2[m] = cc * avm * uvm;
        __syncthreads();

        // raw_i = sum_mm W2[mm,i] g1[mm] + Pn[mm,i] g2[mm]; mm split 2 halves
        int i = tid & 127, half = tid >> 7;
        int mmlo = half * 128;
        float raw = 0.f;
        #pragma unroll 8
        for (int mm = mmlo; mm < mmlo + 128; ++mm)
            raw += W2[mm * 128 + i] * g1[mm] + pnb[mm * 128 + i] * g2[mm];
        red[tid] = raw;
        __syncthreads();

        // Only now wait for the 36 producer blocks of this b.
        if (tid == 0) {
            while (atomicAdd(&cnt[b], 0) < 36) __builtin_amdgcn_s_sleep(2);
            __threadfence();
            float tot = atomicAdd(&ws[OFF_SUM + b], 0.0f);  // coherent read
            snrm[0] = sqrtf(fmaxf(2.f * tot, 0.f));
        }
        __syncthreads();
        if (tid < 128) {
            float rawt = red[tid] + red[tid + 128];
            float vn = ws[OFF_VN + b];
            float a  = -0.5f * rawt / ((snrm[0] + 1e-6f) * (vn + 1e-6f));
            out[(16 + b) * 128 + tid] = a - 0.1f * state[b * 128 + tid];
        }
        return;
    }

    // ================= producer path =================
    int q   = blk - 16;
    int idx = q >> 4;          // 0..35 triangular tile
    int b   = q & 15;
    int tj = 0;
    while ((tj + 1) * (tj + 2) / 2 <= idx) ++tj;
    int ti = idx - tj * (tj + 1) / 2;      // ti <= tj
    int mi0 = ti * 32, mj0 = tj * 32;
    float* PiT = lds;              // [64][32] per round
    float* PjT = lds + 2048;
    float* WiT = lds + 4096;
    float* WjT = lds + 6144;
    const float* ptb  = ws + OFF_PT + b * 32768;
    const float* W2T  = ws + OFF_W2T;
    const float* Smat = ws + OFF_S;
    const float* Qmat = ws + OFF_Q;
    int jr = tid >> 3, jc4 = (tid & 7) * 4;
    int w = tid >> 6, s = tid & 63;
    int ty = s >> 3, tx = s & 7;
    float r[4][4] = {}, f[4][4] = {}, g[4][4] = {};
    // Two staging rounds; round rr stages global j = 32*(l>>4)+16*rr+(l&15)
    // for local row l in [0,64): wave w's rows [16w,16w+16) are global
    // j in [32w+16rr, +16) -> same per-wave j set & order as R8.
    #pragma unroll
    for (int rr = 0; rr < 2; ++rr) {
        #pragma unroll
        for (int it = 0; it < 2; ++it) {
            int l = jr + 32 * it;
            int j = 32 * (l >> 4) + 16 * rr + (l & 15);
            *(float4*)&PiT[l * 32 + jc4] = *(const float4*)&ptb[j * 256 + mi0 + jc4];
            *(float4*)&PjT[l * 32 + jc4] = *(const float4*)&ptb[j * 256 + mj0 + jc4];
            *(float4*)&WiT[l * 32 + jc4] = *(const float4*)&W2T[j * 256 + mi0 + jc4];
            *(float4*)&WjT[l * 32 + jc4] = *(const float4*)&W2T[j * 256 + mj0 + jc4];
        }
        __syncthreads();
        #pragma unroll 4
        for (int jj = 0; jj < 16; ++jj) {
            int l = 16 * w + jj;
            float4 pi4 = *(const float4*)&PiT[l * 32 + 4 * ty];
            float4 pj4 = *(const float4*)&PjT[l * 32 + 4 * tx];
            float4 wi4 = *(const float4*)&WiT[l * 32 + 4 * ty];
            float4 wj4 = *(const float4*)&WjT[l * 32 + 4 * tx];
            float pi[4] = {pi4.x, pi4.y, pi4.z, pi4.w};
            float pj[4] = {pj4.x, pj4.y, pj4.z, pj4.w};
            float wi[4] = {wi4.x, wi4.y, wi4.z, wi4.w};
            float wj[4] = {wj4.x, wj4.y, wj4.z, wj4.w};
            #pragma unroll
            for (int ii = 0; ii < 4; ++ii)
                #pragma unroll
                for (int kk = 0; kk < 4; ++kk) {
                    r[ii][kk] += pi[ii] * pj[kk];   // R[mi,mj]
                    f[ii][kk] += pi[ii] * wj[kk];   // M[mi,mj]
                    g[ii][kk] += pj[kk] * wi[ii];   // M[mj,mi]
                }
        }
        __syncthreads();   // round rr done; safe to restage / reuse as scratch
    }
    // 3-wave scratch: waves 1..3 spill; wave 0 keeps registers.
    if (w != 0) {
        float* scr = lds;
        int base = ((w - 1) * 64 + s) * 49;   // stride 49: conflict-light
        #pragma unroll
        for (int ii = 0; ii < 4; ++ii)
            #pragma unroll
            for (int kk = 0; kk < 4; ++kk) {
                scr[base + ii * 4 + kk]      = r[ii][kk];
                scr[base + 16 + ii * 4 + kk] = f[ii][kk];
                scr[base + 32 + ii * 4 + kk] = g[ii][kk];
            }
    }
    __syncthreads();
    if (tid < 64) {
        float tr[16], tf[16], tg[16];
        #pragma unroll
        for (int ii = 0; ii < 4; ++ii)
            #pragma unroll
            for (int kk = 0; kk < 4; ++kk) {
                tr[ii * 4 + kk] = r[ii][kk];
                tf[ii * 4 + kk] = f[ii][kk];
                tg[ii * 4 + kk] = g[ii][kk];
            }
        // add waves 1..3 in order -> same w0+w1+w2+w3 order as R8
        for (int ww = 0; ww < 3; ++ww) {
            const float* sc = lds + (ww * 64 + tid) * 49;
            #pragma unroll
            for (int k = 0; k < 16; ++k) {
                tr[k] += sc[k];
                tf[k] += sc[16 + k];
                tg[k] += sc[32 + k];
            }
        }
        const float* cb = ws + OFF_C + b * 256;
        int mi = mi0 + 4 * (tid >> 3), mj = mj0 + 4 * (tid & 7);
        float4 ce4 = *(const float4*)&cb[mj];
        float ce[4] = {ce4.x, ce4.y, ce4.z, ce4.w};
        float sum = 0.f;
        #pragma unroll
        for (int ii = 0; ii < 4; ++ii) {
            float ci = cb[mi + ii];
            float4 S4 = *(const float4*)&Smat[(mi + ii) * 256 + mj];
            float4 Q4 = *(const float4*)&Qmat[(mi + ii) * 256 + mj];
            float Sv[4] = {S4.x, S4.y, S4.z, S4.w};
            float Qv[4] = {Q4.x, Q4.y, Q4.z, Q4.w};
            #pragma unroll
            for (int kk = 0; kk < 4; ++kk)
                sum += ci * ce[kk] * Sv[kk] * (Qv[kk] * tr[ii * 4 + kk] + tf[ii * 4 + kk] * tg[ii * 4 + kk]);
        }
        if (ti < tj) sum *= 2.f;
        #pragma unroll
        for (int off = 32; off > 0; off >>= 1)
            sum += __shfl_down(sum, off);
        if (tid == 0) {
            atomicAdd(&ws[OFF_SUM + b], sum);
            __threadfence();
            atomicAdd(&cnt[b], 1);   // release: epilogue block b may finish
        }
    }
}

extern "C" void kernel_launch(void* const* d_in, const int* in_sizes, int n_in,
                              void* d_out, int out_size, void* d_ws, size_t ws_size,
                              hipStream_t stream) {
    (void)in_sizes; (void)n_in; (void)out_size; (void)ws_size;
    const float* t     = (const float*)d_in[0];
    const float* state = (const float*)d_in[1];
    const float* x0    = (const float*)d_in[2];
    const float* x1    = (const float*)d_in[3];
    const float* W1    = (const float*)d_in[4];
    const float* b1    = (const float*)d_in[5];
    const float* W2    = (const float*)d_in[6];
    // b2 cancels in the Jacobian — unused.
    float* out = (float*)d_out;
    float* ws  = (float*)d_ws;

    k_stage1c<<<384, 256, 0, stream>>>(t, state, x0, x1, W1, b1, W2, ws, out);
    k_fnorm7<<<592, 256, 0, stream>>>(state, W2, ws, out);
}